// Round 4
// baseline (728.626 us; speedup 1.0000x reference)
//
#include <hip/hip_runtime.h>

// GCN 3-layer forward, fp32. N=100000 nodes, E=1.6M edges, HID=128, N_CLS=40.
// Workspace layout: Y[N*128] f32 | H[N*128] f32 | csr[E] i32 | rowptr[N+1] i32 |
// deg[N] i32 | cursor[N] i32 | norm[N] f32 | maskflag i32 | part[nb] i32

__global__ void k_deg(const int* __restrict__ dst, int* __restrict__ deg, int E) {
    int e = blockIdx.x * 256 + threadIdx.x;
    if (e < E) atomicAdd(&deg[dst[e]], 1);
}

// --- parallel prefix sum over deg (3 kernels, 1024 elements/block) ---
__global__ __launch_bounds__(256) void k_part(const int* __restrict__ deg,
                                              int* __restrict__ part, int n) {
    __shared__ int red[256];
    int t = threadIdx.x;
    int base = blockIdx.x * 1024 + t * 4;
    int s = 0;
#pragma unroll
    for (int j = 0; j < 4; ++j) {
        int i = base + j;
        if (i < n) s += deg[i];
    }
    red[t] = s;
    __syncthreads();
    for (int off = 128; off > 0; off >>= 1) {
        if (t < off) red[t] += red[t + off];
        __syncthreads();
    }
    if (t == 0) part[blockIdx.x] = red[0];
}

__global__ __launch_bounds__(256) void k_scanpart(int* __restrict__ part,
                                                  int* __restrict__ rowptr,
                                                  int nb, int n) {
    __shared__ int buf[1024];
    int t = threadIdx.x;
    for (int i = t; i < nb; i += 256) buf[i] = part[i];
    __syncthreads();
    if (t == 0) {
        int run = 0;
        for (int i = 0; i < nb; ++i) {
            int v = buf[i];
            buf[i] = run;
            run += v;
        }
        rowptr[n] = run;  // == E
    }
    __syncthreads();
    for (int i = t; i < nb; i += 256) part[i] = buf[i];
}

__global__ __launch_bounds__(256) void k_rowptr(const int* __restrict__ deg,
                                                const int* __restrict__ part,
                                                int* __restrict__ rowptr,
                                                float* __restrict__ normv, int n) {
    __shared__ int ts[256];
    int t = threadIdx.x;
    int base = blockIdx.x * 1024 + t * 4;
    int d[4];
    int s = 0;
#pragma unroll
    for (int j = 0; j < 4; ++j) {
        int i = base + j;
        d[j] = (i < n) ? deg[i] : 0;
        s += d[j];
    }
    ts[t] = s;
    __syncthreads();
    for (int off = 1; off < 256; off <<= 1) {
        int v = (t >= off) ? ts[t - off] : 0;
        __syncthreads();
        ts[t] += v;
        __syncthreads();
    }
    int run = part[blockIdx.x] + ((t == 0) ? 0 : ts[t - 1]);
#pragma unroll
    for (int j = 0; j < 4; ++j) {
        int i = base + j;
        if (i < n) {
            rowptr[i] = run;
            normv[i] = 1.0f / fmaxf((float)d[j], 1.0f);
            run += d[j];
        }
    }
}

__global__ void k_scatter(const int* __restrict__ src, const int* __restrict__ dst,
                          const int* __restrict__ rowptr, int* __restrict__ cursor,
                          int* __restrict__ csr, int E) {
    int e = blockIdx.x * 256 + threadIdx.x;
    if (e < E) {
        int d = dst[e];
        int p = atomicAdd(&cursor[d], 1);
        csr[rowptr[d] + p] = src[e];
    }
}

// Detect mask dtype: any word >1 in first 1024 words -> packed bytes (bool).
__global__ void k_maskdet(const unsigned* __restrict__ m, int* __restrict__ flag) {
    unsigned v = m[blockIdx.x * 256 + threadIdx.x];
    if (v > 1u) atomicOr(flag, 1);
}

// Y[r][c] = sum_k X[r][k] * W[k][c].  K=128 in two 64-wide chunks, LDS <= 64KB.
template<int BN>
__global__ __launch_bounds__(256) void k_gemm(const float* __restrict__ X,
                                              const float* __restrict__ Wg,
                                              float* __restrict__ Y,
                                              int nrows, int wcols) {
    constexpr int TN = BN / 16;  // 8 or 4
    __shared__ float Xs[128][64];
    __shared__ float Ws[64][BN];
    int t = threadIdx.x;
    int bm = blockIdx.x * 128;
    int tx = t & 15, ty = t >> 4;
    int sw = (ty & 3) << 2;

    float acc[8][TN];
#pragma unroll
    for (int i = 0; i < 8; ++i)
#pragma unroll
        for (int j = 0; j < TN; ++j) acc[i][j] = 0.0f;

    for (int kc = 0; kc < 128; kc += 64) {
        for (int idx = t; idx < 128 * 16; idx += 256) {
            int row = idx >> 4, k4 = idx & 15;
            int grow = bm + row;
            if (grow >= nrows) grow = nrows - 1;
            float4 v = *(const float4*)(X + (size_t)grow * 128 + kc + k4 * 4);
            int kk2 = (k4 * 4) ^ (((row >> 3) & 3) << 2);
            *(float4*)&Xs[row][kk2] = v;
        }
        if (BN == 128) {
            for (int idx = t; idx < 64 * 32; idx += 256) {
                int k = idx >> 5, c4 = idx & 31;
                *(float4*)&Ws[k][c4 * 4] =
                    *(const float4*)(Wg + (size_t)(kc + k) * 128 + c4 * 4);
            }
        } else {
            for (int idx = t; idx < 64 * BN; idx += 256) {
                int k = idx / BN, c = idx % BN;
                Ws[k][c] = (c < wcols) ? Wg[(size_t)(kc + k) * wcols + c] : 0.0f;
            }
        }
        __syncthreads();

        for (int k = 0; k < 64; k += 4) {
            float4 a4[8];
#pragma unroll
            for (int i = 0; i < 8; ++i)
                a4[i] = *(const float4*)&Xs[ty * 8 + i][k ^ sw];
#pragma unroll
            for (int kk = 0; kk < 4; ++kk) {
                float b[TN];
                *(float4*)&b[0] = *(const float4*)&Ws[k + kk][tx * 4];
                if (BN == 128)
                    *(float4*)&b[4] = *(const float4*)&Ws[k + kk][64 + tx * 4];
#pragma unroll
                for (int i = 0; i < 8; ++i) {
                    float a = ((const float*)&a4[i])[kk];
#pragma unroll
                    for (int j = 0; j < TN; ++j) acc[i][j] += a * b[j];
                }
            }
        }
        __syncthreads();
    }

#pragma unroll
    for (int i = 0; i < 8; ++i) {
        int r = bm + ty * 8 + i;
        if (r < nrows) {
            *(float4*)(Y + (size_t)r * BN + tx * 4) = *(const float4*)&acc[i][0];
            if (BN == 128)
                *(float4*)(Y + (size_t)r * BN + 64 + tx * 4) = *(const float4*)&acc[i][4];
        }
    }
}

// Feature-chunked SpMM: grid (ceil(N/8), 4). Each 32-lane group = one dst node
// x one 32-col chunk (128B sub-row gathers -> per-pass distinct-line working
// set 12.8MB instead of 51.2MB). blockIdx.x fastest -> chunk passes grouped.
template<bool ACT>
__global__ __launch_bounds__(256) void k_spmm_c(const float* __restrict__ Y,
                       const int* __restrict__ rowptr, const int* __restrict__ csr,
                       const float* __restrict__ normv, const float* __restrict__ bias,
                       const void* __restrict__ mask, const int* __restrict__ mflag,
                       float* __restrict__ H, int N) {
    int g = threadIdx.x >> 5;
    int lane = threadIdx.x & 31;
    int i = blockIdx.x * 8 + g;
    if (i >= N) return;
    int c = blockIdx.y * 32 + lane;
    int lo = rowptr[i], hi = rowptr[i + 1];
    float acc = 0.0f;
    int e = lo;
    for (; e + 3 < hi; e += 4) {
        int s0 = csr[e], s1 = csr[e + 1], s2 = csr[e + 2], s3 = csr[e + 3];
        acc += Y[(size_t)s0 * 128 + c];
        acc += Y[(size_t)s1 * 128 + c];
        acc += Y[(size_t)s2 * 128 + c];
        acc += Y[(size_t)s3 * 128 + c];
    }
    for (; e < hi; ++e) acc += Y[(size_t)csr[e] * 128 + c];
    float v = acc * normv[i] + bias[c];
    if (ACT) {
        v = fmaxf(v, 0.0f);
        size_t j = (size_t)i * 128 + c;
        bool keep;
        if (*mflag != 0) keep = ((const unsigned char*)mask)[j] != 0;
        else             keep = ((const int*)mask)[j] != 0;
        v = keep ? v * 2.0f : 0.0f;  // KEEP=0.5 -> /0.5
    }
    H[(size_t)i * 128 + c] = v;
}

// Unchunked SpMM for the 40-wide final layer (writes d_out directly).
__global__ void k_spmm40(const float* __restrict__ Y, int ldy,
                         const int* __restrict__ rowptr, const int* __restrict__ csr,
                         const float* __restrict__ normv, const float* __restrict__ bias,
                         float* __restrict__ H, int width) {
    int i = blockIdx.x;
    int c = threadIdx.x;
    if (c >= width) return;
    int lo = rowptr[i], hi = rowptr[i + 1];
    float acc = 0.0f;
    int e = lo;
    for (; e + 3 < hi; e += 4) {
        int s0 = csr[e], s1 = csr[e + 1], s2 = csr[e + 2], s3 = csr[e + 3];
        acc += Y[(size_t)s0 * ldy + c];
        acc += Y[(size_t)s1 * ldy + c];
        acc += Y[(size_t)s2 * ldy + c];
        acc += Y[(size_t)s3 * ldy + c];
    }
    for (; e < hi; ++e) acc += Y[(size_t)csr[e] * ldy + c];
    H[(size_t)i * width + c] = acc * normv[i] + bias[c];
}

extern "C" void kernel_launch(void* const* d_in, const int* in_sizes, int n_in,
                              void* d_out, int out_size, void* d_ws, size_t ws_size,
                              hipStream_t stream) {
    const float* feat = (const float*)d_in[0];
    const int* src = (const int*)d_in[1];
    const int* dst = (const int*)d_in[2];
    const void* mask1 = d_in[3];
    const void* mask2 = d_in[4];
    const float* w0 = (const float*)d_in[5];
    const float* b0 = (const float*)d_in[6];
    const float* w1 = (const float*)d_in[7];
    const float* b1 = (const float*)d_in[8];
    const float* w2 = (const float*)d_in[9];
    const float* b2 = (const float*)d_in[10];
    int N = in_sizes[0] / 128;
    int E = in_sizes[1];
    int ncls = in_sizes[10];  // 40

    float* out = (float*)d_out;
    float* Y = (float*)d_ws;
    float* H = Y + (size_t)N * 128;
    int* csr = (int*)(H + (size_t)N * 128);
    int* rowptr = csr + E;
    int* deg = rowptr + (N + 1);
    int* cursor = deg + N;
    float* normv = (float*)(cursor + N);
    int* mflag = (int*)(normv + N);
    int* part = mflag + 1;

    int nb = (N + 1023) / 1024;  // 98

    hipMemsetAsync(deg, 0, (size_t)N * 4, stream);
    hipMemsetAsync(cursor, 0, (size_t)N * 4, stream);
    hipMemsetAsync(mflag, 0, 4, stream);
    k_maskdet<<<4, 256, 0, stream>>>((const unsigned*)mask1, mflag);
    int eb = (E + 255) / 256;
    k_deg<<<eb, 256, 0, stream>>>(dst, deg, E);
    k_part<<<nb, 256, 0, stream>>>(deg, part, N);
    k_scanpart<<<1, 256, 0, stream>>>(part, rowptr, nb, N);
    k_rowptr<<<nb, 256, 0, stream>>>(deg, part, rowptr, normv, N);
    k_scatter<<<eb, 256, 0, stream>>>(src, dst, rowptr, cursor, csr, E);

    int gb = (N + 127) / 128;
    dim3 sgrid((N + 7) / 8, 4);
    k_gemm<128><<<gb, 256, 0, stream>>>(feat, w0, Y, N, 128);
    k_spmm_c<true><<<sgrid, 256, 0, stream>>>(Y, rowptr, csr, normv, b0, mask1, mflag, H, N);
    k_gemm<128><<<gb, 256, 0, stream>>>(H, w1, Y, N, 128);
    k_spmm_c<true><<<sgrid, 256, 0, stream>>>(Y, rowptr, csr, normv, b1, mask2, mflag, H, N);
    k_gemm<64><<<gb, 256, 0, stream>>>(H, w2, Y, N, ncls);
    k_spmm40<<<N, 64, 0, stream>>>(Y, 64, rowptr, csr, normv, b2, out, ncls);
}

// Round 5
// 649.379 us; speedup vs baseline: 1.1220x; 1.1220x over previous
//
#include <hip/hip_runtime.h>

// GCN 3-layer forward, fp32. N=100000 nodes, E=1.6M edges, HID=128, N_CLS=40.
// Workspace layout: Y[N*128] f32 | H[N*128] f32 | csr[E] i32 | rowptr[N+1] i32 |
// deg[N] i32 | cursor[N] i32 | norm[N] f32 | maskflag i32 | part[nb] i32

__global__ void k_deg(const int* __restrict__ dst, int* __restrict__ deg, int E) {
    int e = blockIdx.x * 256 + threadIdx.x;
    if (e < E) atomicAdd(&deg[dst[e]], 1);
}

// --- parallel prefix sum over deg (3 kernels, 1024 elements/block) ---
__global__ __launch_bounds__(256) void k_part(const int* __restrict__ deg,
                                              int* __restrict__ part, int n) {
    __shared__ int red[256];
    int t = threadIdx.x;
    int base = blockIdx.x * 1024 + t * 4;
    int s = 0;
#pragma unroll
    for (int j = 0; j < 4; ++j) {
        int i = base + j;
        if (i < n) s += deg[i];
    }
    red[t] = s;
    __syncthreads();
    for (int off = 128; off > 0; off >>= 1) {
        if (t < off) red[t] += red[t + off];
        __syncthreads();
    }
    if (t == 0) part[blockIdx.x] = red[0];
}

__global__ __launch_bounds__(256) void k_scanpart(int* __restrict__ part,
                                                  int* __restrict__ rowptr,
                                                  int nb, int n) {
    __shared__ int buf[1024];
    int t = threadIdx.x;
    for (int i = t; i < nb; i += 256) buf[i] = part[i];
    __syncthreads();
    if (t == 0) {
        int run = 0;
        for (int i = 0; i < nb; ++i) {
            int v = buf[i];
            buf[i] = run;
            run += v;
        }
        rowptr[n] = run;  // == E
    }
    __syncthreads();
    for (int i = t; i < nb; i += 256) part[i] = buf[i];
}

__global__ __launch_bounds__(256) void k_rowptr(const int* __restrict__ deg,
                                                const int* __restrict__ part,
                                                int* __restrict__ rowptr,
                                                float* __restrict__ normv, int n) {
    __shared__ int ts[256];
    int t = threadIdx.x;
    int base = blockIdx.x * 1024 + t * 4;
    int d[4];
    int s = 0;
#pragma unroll
    for (int j = 0; j < 4; ++j) {
        int i = base + j;
        d[j] = (i < n) ? deg[i] : 0;
        s += d[j];
    }
    ts[t] = s;
    __syncthreads();
    for (int off = 1; off < 256; off <<= 1) {
        int v = (t >= off) ? ts[t - off] : 0;
        __syncthreads();
        ts[t] += v;
        __syncthreads();
    }
    int run = part[blockIdx.x] + ((t == 0) ? 0 : ts[t - 1]);
#pragma unroll
    for (int j = 0; j < 4; ++j) {
        int i = base + j;
        if (i < n) {
            rowptr[i] = run;
            normv[i] = 1.0f / fmaxf((float)d[j], 1.0f);
            run += d[j];
        }
    }
}

__global__ void k_scatter(const int* __restrict__ src, const int* __restrict__ dst,
                          const int* __restrict__ rowptr, int* __restrict__ cursor,
                          int* __restrict__ csr, int E) {
    int e = blockIdx.x * 256 + threadIdx.x;
    if (e < E) {
        int d = dst[e];
        int p = atomicAdd(&cursor[d], 1);
        csr[rowptr[d] + p] = src[e];
    }
}

// Detect mask dtype: any word >1 in first 1024 words -> packed bytes (bool).
__global__ void k_maskdet(const unsigned* __restrict__ m, int* __restrict__ flag) {
    unsigned v = m[blockIdx.x * 256 + threadIdx.x];
    if (v > 1u) atomicOr(flag, 1);
}

// Y[r][c] = sum_k X[r][k] * W[k][c].  K=128 in two 64-wide chunks, LDS <= 64KB.
template<int BN>
__global__ __launch_bounds__(256) void k_gemm(const float* __restrict__ X,
                                              const float* __restrict__ Wg,
                                              float* __restrict__ Y,
                                              int nrows, int wcols) {
    constexpr int TN = BN / 16;  // 8 or 4
    __shared__ float Xs[128][64];
    __shared__ float Ws[64][BN];
    int t = threadIdx.x;
    int bm = blockIdx.x * 128;
    int tx = t & 15, ty = t >> 4;
    int sw = (ty & 3) << 2;

    float acc[8][TN];
#pragma unroll
    for (int i = 0; i < 8; ++i)
#pragma unroll
        for (int j = 0; j < TN; ++j) acc[i][j] = 0.0f;

    for (int kc = 0; kc < 128; kc += 64) {
        for (int idx = t; idx < 128 * 16; idx += 256) {
            int row = idx >> 4, k4 = idx & 15;
            int grow = bm + row;
            if (grow >= nrows) grow = nrows - 1;
            float4 v = *(const float4*)(X + (size_t)grow * 128 + kc + k4 * 4);
            int kk2 = (k4 * 4) ^ (((row >> 3) & 3) << 2);
            *(float4*)&Xs[row][kk2] = v;
        }
        if (BN == 128) {
            for (int idx = t; idx < 64 * 32; idx += 256) {
                int k = idx >> 5, c4 = idx & 31;
                *(float4*)&Ws[k][c4 * 4] =
                    *(const float4*)(Wg + (size_t)(kc + k) * 128 + c4 * 4);
            }
        } else {
            for (int idx = t; idx < 64 * BN; idx += 256) {
                int k = idx / BN, c = idx % BN;
                Ws[k][c] = (c < wcols) ? Wg[(size_t)(kc + k) * wcols + c] : 0.0f;
            }
        }
        __syncthreads();

        for (int k = 0; k < 64; k += 4) {
            float4 a4[8];
#pragma unroll
            for (int i = 0; i < 8; ++i)
                a4[i] = *(const float4*)&Xs[ty * 8 + i][k ^ sw];
#pragma unroll
            for (int kk = 0; kk < 4; ++kk) {
                float b[TN];
                *(float4*)&b[0] = *(const float4*)&Ws[k + kk][tx * 4];
                if (BN == 128)
                    *(float4*)&b[4] = *(const float4*)&Ws[k + kk][64 + tx * 4];
#pragma unroll
                for (int i = 0; i < 8; ++i) {
                    float a = ((const float*)&a4[i])[kk];
#pragma unroll
                    for (int j = 0; j < TN; ++j) acc[i][j] += a * b[j];
                }
            }
        }
        __syncthreads();
    }

#pragma unroll
    for (int i = 0; i < 8; ++i) {
        int r = bm + ty * 8 + i;
        if (r < nrows) {
            *(float4*)(Y + (size_t)r * BN + tx * 4) = *(const float4*)&acc[i][0];
            if (BN == 128)
                *(float4*)(Y + (size_t)r * BN + 64 + tx * 4) = *(const float4*)&acc[i][4];
        }
    }
}

// SpMM, one WAVE per dst node, float2 per lane (64 lanes x 8B = 512B row in
// one instruction per edge). 4 nodes per 256-thread block. Unroll 4 edges ->
// 4x512B in flight per wave. mflag: 0 -> int32 mask, 1 -> byte mask.
template<bool ACT>
__global__ __launch_bounds__(256) void k_spmmw(const float* __restrict__ Y,
                       const int* __restrict__ rowptr, const int* __restrict__ csr,
                       const float* __restrict__ normv, const float* __restrict__ bias,
                       const void* __restrict__ mask, const int* __restrict__ mflag,
                       float* __restrict__ H, int N) {
    int wid = threadIdx.x >> 6;
    int lane = threadIdx.x & 63;
    int i = blockIdx.x * 4 + wid;
    if (i >= N) return;
    int c = lane * 2;
    int lo = rowptr[i], hi = rowptr[i + 1];
    float2 acc = {0.0f, 0.0f};
    int e = lo;
    for (; e + 3 < hi; e += 4) {
        int s0 = csr[e], s1 = csr[e + 1], s2 = csr[e + 2], s3 = csr[e + 3];
        float2 v0 = *(const float2*)(Y + (size_t)s0 * 128 + c);
        float2 v1 = *(const float2*)(Y + (size_t)s1 * 128 + c);
        float2 v2 = *(const float2*)(Y + (size_t)s2 * 128 + c);
        float2 v3 = *(const float2*)(Y + (size_t)s3 * 128 + c);
        acc.x += v0.x + v1.x + v2.x + v3.x;
        acc.y += v0.y + v1.y + v2.y + v3.y;
    }
    for (; e < hi; ++e) {
        float2 v = *(const float2*)(Y + (size_t)csr[e] * 128 + c);
        acc.x += v.x;
        acc.y += v.y;
    }
    float nrm = normv[i];
    float2 b = *(const float2*)&bias[c];
    float vx = acc.x * nrm + b.x;
    float vy = acc.y * nrm + b.y;
    if (ACT) {
        vx = fmaxf(vx, 0.0f);
        vy = fmaxf(vy, 0.0f);
        size_t j = (size_t)i * 128 + c;
        bool k0, k1;
        if (*mflag != 0) {
            const unsigned char* m = (const unsigned char*)mask;
            k0 = m[j] != 0; k1 = m[j + 1] != 0;
        } else {
            const int* m = (const int*)mask;
            k0 = m[j] != 0; k1 = m[j + 1] != 0;
        }
        vx = k0 ? vx * 2.0f : 0.0f;  // KEEP=0.5 -> /0.5
        vy = k1 ? vy * 2.0f : 0.0f;
    }
    *(float2*)(H + (size_t)i * 128 + c) = make_float2(vx, vy);
}

// Layer-3 SpMM: wave per node, lanes 0..19 hold float2 (40 cols). Y stride 64.
__global__ __launch_bounds__(256) void k_spmm40w(const float* __restrict__ Y,
                        const int* __restrict__ rowptr, const int* __restrict__ csr,
                        const float* __restrict__ normv, const float* __restrict__ bias,
                        float* __restrict__ H, int N, int width) {
    int wid = threadIdx.x >> 6;
    int lane = threadIdx.x & 63;
    int i = blockIdx.x * 4 + wid;
    if (i >= N) return;
    int c = lane * 2;
    if (c >= width) return;
    int lo = rowptr[i], hi = rowptr[i + 1];
    float2 acc = {0.0f, 0.0f};
    int e = lo;
    for (; e + 3 < hi; e += 4) {
        int s0 = csr[e], s1 = csr[e + 1], s2 = csr[e + 2], s3 = csr[e + 3];
        float2 v0 = *(const float2*)(Y + (size_t)s0 * 64 + c);
        float2 v1 = *(const float2*)(Y + (size_t)s1 * 64 + c);
        float2 v2 = *(const float2*)(Y + (size_t)s2 * 64 + c);
        float2 v3 = *(const float2*)(Y + (size_t)s3 * 64 + c);
        acc.x += v0.x + v1.x + v2.x + v3.x;
        acc.y += v0.y + v1.y + v2.y + v3.y;
    }
    for (; e < hi; ++e) {
        float2 v = *(const float2*)(Y + (size_t)csr[e] * 64 + c);
        acc.x += v.x;
        acc.y += v.y;
    }
    float nrm = normv[i];
    float vx = acc.x * nrm + bias[c];
    float vy = acc.y * nrm + bias[c + 1];
    *(float2*)(H + (size_t)i * width + c) = make_float2(vx, vy);
}

extern "C" void kernel_launch(void* const* d_in, const int* in_sizes, int n_in,
                              void* d_out, int out_size, void* d_ws, size_t ws_size,
                              hipStream_t stream) {
    const float* feat = (const float*)d_in[0];
    const int* src = (const int*)d_in[1];
    const int* dst = (const int*)d_in[2];
    const void* mask1 = d_in[3];
    const void* mask2 = d_in[4];
    const float* w0 = (const float*)d_in[5];
    const float* b0 = (const float*)d_in[6];
    const float* w1 = (const float*)d_in[7];
    const float* b1 = (const float*)d_in[8];
    const float* w2 = (const float*)d_in[9];
    const float* b2 = (const float*)d_in[10];
    int N = in_sizes[0] / 128;
    int E = in_sizes[1];
    int ncls = in_sizes[10];  // 40

    float* out = (float*)d_out;
    float* Y = (float*)d_ws;
    float* H = Y + (size_t)N * 128;
    int* csr = (int*)(H + (size_t)N * 128);
    int* rowptr = csr + E;
    int* deg = rowptr + (N + 1);
    int* cursor = deg + N;
    float* normv = (float*)(cursor + N);
    int* mflag = (int*)(normv + N);
    int* part = mflag + 1;

    int nb = (N + 1023) / 1024;  // 98

    hipMemsetAsync(deg, 0, (size_t)N * 4, stream);
    hipMemsetAsync(cursor, 0, (size_t)N * 4, stream);
    hipMemsetAsync(mflag, 0, 4, stream);
    k_maskdet<<<4, 256, 0, stream>>>((const unsigned*)mask1, mflag);
    int eb = (E + 255) / 256;
    k_deg<<<eb, 256, 0, stream>>>(dst, deg, E);
    k_part<<<nb, 256, 0, stream>>>(deg, part, N);
    k_scanpart<<<1, 256, 0, stream>>>(part, rowptr, nb, N);
    k_rowptr<<<nb, 256, 0, stream>>>(deg, part, rowptr, normv, N);
    k_scatter<<<eb, 256, 0, stream>>>(src, dst, rowptr, cursor, csr, E);

    int gb = (N + 127) / 128;
    int sb = (N + 3) / 4;
    k_gemm<128><<<gb, 256, 0, stream>>>(feat, w0, Y, N, 128);
    k_spmmw<true><<<sb, 256, 0, stream>>>(Y, rowptr, csr, normv, b0, mask1, mflag, H, N);
    k_gemm<128><<<gb, 256, 0, stream>>>(H, w1, Y, N, 128);
    k_spmmw<true><<<sb, 256, 0, stream>>>(Y, rowptr, csr, normv, b1, mask2, mflag, H, N);
    k_gemm<64><<<gb, 256, 0, stream>>>(H, w2, Y, N, ncls);
    k_spmm40w<<<sb, 256, 0, stream>>>(Y, rowptr, csr, normv, b2, out, N, ncls);
}